// Round 6
// baseline (83.536 us; speedup 1.0000x reference)
//
#include <hip/hip_runtime.h>
#include <hip/hip_cooperative_groups.h>

namespace cg = cooperative_groups;

// SurvRankingLoss: loss = -mean over comparable pairs of sigmoid(z_i - z_j)
// comparable(i,j) = (t_i < t_j) && (event_i > 0), event = 1 - censorship.
// B = 8192. O(B^2) VALU work is only ~5 us; measured per-dispatch graph
// overhead is ~5 us, so fuse everything into ONE cooperative dispatch:
//   phase 1: per (i-block, j-chunk) tile — stage j-tile {t_j, exp(z_j)},
//            block-local compaction of event i-rows (deterministic), dense
//            pair loop with sigmoid = e_i/(e_i+e_j); partial -> P[bid].
//   grid.sync()
//   phase 2: block 0 reduces 1024 partials in fixed order (double).
// Determinism: fixed partitioning, fixed reduction order, every ws cell read
// was written this call. No atomics, no memsets.

constexpr int THREADS = 256;
constexpr int JT = 256;   // j-tile per block

__global__ __launch_bounds__(256) void surv_all(
    const float* __restrict__ z, const float* __restrict__ ct,
    float2* __restrict__ P, float* __restrict__ out, int njc)
{
    __shared__ float s_t[JT];        // t_j
    __shared__ float s_e[JT];        // exp(z_j)
    __shared__ float s_tg[THREADS];  // compacted t_i (event rows)
    __shared__ float s_ei[THREADS];  // compacted exp(z_i)
    __shared__ int   s_wcnt[4];
    __shared__ float wsum[4];
    __shared__ int   wcnt2[4];
    __shared__ double ss[THREADS];
    __shared__ double sc[THREADS];

    const int tid = threadIdx.x;
    const int ib  = blockIdx.x / njc;   // i-block
    const int jc  = blockIdx.x % njc;   // j-chunk
    const int j0  = jc * JT;

    // ---- phase 1: pair partial for this (i-block, j-chunk) tile ----
    {
        const int j = j0 + tid;
        s_t[tid] = ct[2 * j + 1];
        s_e[tid] = __expf(z[j]);
    }

    const int i = ib * THREADS + tid;
    const float cens = ct[2 * i];
    const float ti   = ct[2 * i + 1];
    const float eii  = __expf(z[i]);
    const bool  ev   = (1.0f - cens) > 0.0f;
    const unsigned long long mask = __ballot(ev);
    const int lane = tid & 63;
    const int wid  = tid >> 6;
    if (lane == 0) s_wcnt[wid] = __popcll(mask);
    __syncthreads();
    int base = 0;
    for (int w = 0; w < wid; ++w) base += s_wcnt[w];
    const int m = s_wcnt[0] + s_wcnt[1] + s_wcnt[2] + s_wcnt[3];
    const int pos = base + __popcll(mask & ((1ull << lane) - 1ull));
    if (ev) { s_tg[pos] = ti; s_ei[pos] = eii; }
    __syncthreads();

    const bool act = tid < m;
    float tg = 0.0f, ei = 0.0f;
    if (act) { tg = s_tg[tid]; ei = s_ei[tid]; }

    float fsum = 0.0f;
    int   cnt  = 0;
    if (act) {   // waves past the compacted count skip the loop entirely
        const float4* t4 = reinterpret_cast<const float4*>(s_t);
        const float4* e4 = reinterpret_cast<const float4*>(s_e);
#pragma unroll 8
        for (int q = 0; q < JT / 4; ++q) {
            const float4 t = t4[q];
            const float4 e = e4[q];
            // sigmoid(z_i - z_j) = e_i / (e_i + e_j)
            { bool c = tg < t.x; float sg = ei * __builtin_amdgcn_rcpf(ei + e.x); fsum += c ? sg : 0.0f; cnt += c; }
            { bool c = tg < t.y; float sg = ei * __builtin_amdgcn_rcpf(ei + e.y); fsum += c ? sg : 0.0f; cnt += c; }
            { bool c = tg < t.z; float sg = ei * __builtin_amdgcn_rcpf(ei + e.z); fsum += c ? sg : 0.0f; cnt += c; }
            { bool c = tg < t.w; float sg = ei * __builtin_amdgcn_rcpf(ei + e.w); fsum += c ? sg : 0.0f; cnt += c; }
        }
    }

    for (int off = 32; off > 0; off >>= 1) {
        fsum += __shfl_down(fsum, off);
        cnt  += __shfl_down(cnt, off);
    }
    if (lane == 0) { wsum[wid] = fsum; wcnt2[wid] = cnt; }
    __syncthreads();
    if (tid == 0) {
        const float bs = wsum[0] + wsum[1] + wsum[2] + wsum[3];
        const int   bc = wcnt2[0] + wcnt2[1] + wcnt2[2] + wcnt2[3];
        P[blockIdx.x] = make_float2(bs, (float)bc);
    }

    // ---- grid-wide barrier, then block 0 finalizes ----
    cg::this_grid().sync();

    if (blockIdx.x == 0) {
        const int nb = (int)gridDim.x;
        double s = 0.0, c = 0.0;
        for (int k = tid; k < nb; k += THREADS) {   // fixed per-thread order
            const float2 p = P[k];
            s += p.x; c += p.y;
        }
        ss[tid] = s; sc[tid] = c;
        __syncthreads();
        for (int off = THREADS / 2; off > 0; off >>= 1) {   // fixed tree order
            if (tid < off) { ss[tid] += ss[tid + off]; sc[tid] += sc[tid + off]; }
            __syncthreads();
        }
        if (tid == 0) {
            const double n = sc[0];
            out[0] = (n > 0.0) ? (float)(-(ss[0] / n)) : 0.0f;
        }
    }
}

extern "C" void kernel_launch(void* const* d_in, const int* in_sizes, int n_in,
                              void* d_out, int out_size, void* d_ws, size_t ws_size,
                              hipStream_t stream)
{
    const float* z  = (const float*)d_in[0];   // (B,1) f32
    const float* ct = (const float*)d_in[1];   // (B,2) f32 [censorship, time]
    float* out = (float*)d_out;
    const int B = in_sizes[0];

    const int NB  = B / THREADS;   // 32 i-blocks
    int njc = B / JT;              // 32 j-chunks

    float2* P = (float2*)d_ws;     // per-block partials (sum, count)

    void* args[] = { (void*)&z, (void*)&ct, (void*)&P, (void*)&out, (void*)&njc };
    hipLaunchCooperativeKernel(reinterpret_cast<void*>(surv_all),
                               dim3(NB * njc), dim3(THREADS), args, 0, stream);
}

// Round 7
// 21.380 us; speedup vs baseline: 3.9073x; 3.9073x over previous
//
#include <hip/hip_runtime.h>

// SurvRankingLoss: loss = -mean over comparable pairs of sigmoid(z_i - z_j)
// comparable(i,j) = (t_i < t_j) && (event_i > 0), event = 1 - censorship.
// B = 8192. Two dispatches (cooperative grid.sync measured at ~70 us on this
// chip -> never again). Pairs kernel: per (i-block, j-chunk) tile.
//  - block-local compaction of event i-rows (deterministic),
//  - WAVE->CHUNK ROTATION by blockIdx: compacted rows are chunked 4x64 and
//    wave w takes chunk (w+bid)&3. Without this, active rows (m~128) always
//    land on SIMD0/1 of every co-resident block -> 2x SIMD imbalance.
//  - inner pair: sigmoid(zi-zj) = 1/(1+e_j*ri), ri = exp(-z_i) per lane:
//    fma + rcp + cmp + cndmask-add + carry-add = ~18 cyc/pair.
// fin: single wave, fixed-order double reduction (deterministic).
// No atomics, no memsets; every ws cell read was written this call.

constexpr int THREADS = 256;
constexpr int JT = 256;   // j-tile per block

__global__ __launch_bounds__(256) void surv_pairs(
    const float* __restrict__ z, const float* __restrict__ ct,
    float2* __restrict__ P, int njc)
{
    __shared__ float s_t[JT];        // t_j
    __shared__ float s_e[JT];        // exp(z_j)
    __shared__ float s_tg[THREADS];  // compacted t_i (event rows)
    __shared__ float s_ri[THREADS];  // compacted exp(-z_i)
    __shared__ int   s_wcnt[4];
    __shared__ float wsum[4];
    __shared__ int   wcnt2[4];

    const int tid = threadIdx.x;
    const int ib  = blockIdx.x / njc;   // i-block
    const int jc  = blockIdx.x % njc;   // j-chunk
    const int j0  = jc * JT;

    // stage j-tile
    {
        const int j = j0 + tid;
        s_t[tid] = ct[2 * j + 1];
        s_e[tid] = __expf(z[j]);
    }

    // own i-row + block-local compaction of event rows (deterministic)
    const int i = ib * THREADS + tid;
    const float cens = ct[2 * i];
    const float ti   = ct[2 * i + 1];
    const float rii  = __expf(-z[i]);     // 1/exp(z_i), exact form
    const bool  ev   = (1.0f - cens) > 0.0f;
    const unsigned long long mask = __ballot(ev);
    const int lane = tid & 63;
    const int wid  = tid >> 6;
    if (lane == 0) s_wcnt[wid] = __popcll(mask);
    __syncthreads();
    int base = 0;
    for (int w = 0; w < wid; ++w) base += s_wcnt[w];
    const int m = s_wcnt[0] + s_wcnt[1] + s_wcnt[2] + s_wcnt[3];
    const int pos = base + __popcll(mask & ((1ull << lane) - 1ull));
    if (ev) { s_tg[pos] = ti; s_ri[pos] = rii; }
    __syncthreads();

    // wave->chunk rotation: balance active chunks across SIMDs
    const int chunk = (wid + (int)blockIdx.x) & 3;
    const int row   = chunk * 64 + lane;
    const bool act  = row < m;
    const float tg = act ? s_tg[row] : __builtin_inff();
    const float ri = act ? s_ri[row] : 0.0f;

    float fsum = 0.0f;
    int   cnt  = 0;
    if (chunk * 64 < m) {   // wave-uniform: idle chunks skip entirely
        const float4* t4 = reinterpret_cast<const float4*>(s_t);
        const float4* e4 = reinterpret_cast<const float4*>(s_e);
#pragma unroll 8
        for (int q = 0; q < JT / 4; ++q) {
            const float4 t = t4[q];
            const float4 e = e4[q];
            // sigmoid(z_i - z_j) = 1 / (1 + e_j * exp(-z_i))
            { bool c = tg < t.x; float d = __builtin_fmaf(e.x, ri, 1.0f); float s = __builtin_amdgcn_rcpf(d); fsum += c ? s : 0.0f; cnt += c; }
            { bool c = tg < t.y; float d = __builtin_fmaf(e.y, ri, 1.0f); float s = __builtin_amdgcn_rcpf(d); fsum += c ? s : 0.0f; cnt += c; }
            { bool c = tg < t.z; float d = __builtin_fmaf(e.z, ri, 1.0f); float s = __builtin_amdgcn_rcpf(d); fsum += c ? s : 0.0f; cnt += c; }
            { bool c = tg < t.w; float d = __builtin_fmaf(e.w, ri, 1.0f); float s = __builtin_amdgcn_rcpf(d); fsum += c ? s : 0.0f; cnt += c; }
        }
    }

    // wave (64-lane) reduction
    for (int off = 32; off > 0; off >>= 1) {
        fsum += __shfl_down(fsum, off);
        cnt  += __shfl_down(cnt, off);
    }
    if (lane == 0) { wsum[wid] = fsum; wcnt2[wid] = cnt; }
    __syncthreads();
    if (tid == 0) {
        const float bs = wsum[0] + wsum[1] + wsum[2] + wsum[3];
        const int   bc = wcnt2[0] + wcnt2[1] + wcnt2[2] + wcnt2[3];
        P[blockIdx.x] = make_float2(bs, (float)bc);   // every block writes its slot
    }
}

__global__ __launch_bounds__(64) void surv_fin(
    const float2* __restrict__ P, int nb, float* __restrict__ out)
{
    const int lane = threadIdx.x;
    double s = 0.0, c = 0.0;
    for (int k = lane; k < nb; k += 64) {   // fixed per-lane order
        const float2 p = P[k];
        s += p.x; c += p.y;
    }
    for (int off = 32; off > 0; off >>= 1) {   // fixed tree order
        s += __shfl_down(s, off);
        c += __shfl_down(c, off);
    }
    if (lane == 0)
        out[0] = (c > 0.0) ? (float)(-(s / c)) : 0.0f;
}

extern "C" void kernel_launch(void* const* d_in, const int* in_sizes, int n_in,
                              void* d_out, int out_size, void* d_ws, size_t ws_size,
                              hipStream_t stream)
{
    const float* z  = (const float*)d_in[0];   // (B,1) f32
    const float* ct = (const float*)d_in[1];   // (B,2) f32 [censorship, time]
    float* out = (float*)d_out;
    const int B = in_sizes[0];

    const int NB  = B / THREADS;   // 32 i-blocks
    const int njc = B / JT;        // 32 j-chunks

    float2* P = (float2*)d_ws;     // per-block partials (sum, count)

    surv_pairs<<<NB * njc, THREADS, 0, stream>>>(z, ct, P, njc);
    surv_fin<<<1, 64, 0, stream>>>(P, NB * njc, out);
}